// Round 15
// baseline (122.564 us; speedup 1.0000x reference)
//
#include <hip/hip_runtime.h>
#include <hip/hip_bf16.h>

#define NB 8
#define NC 256
#define NH 128
#define NW 128
#define NR 512
#define NGROUPS 16
#define HP 130
#define NPIX (NH*NW)

// workspace offsets (in floats)
#define OFF_KERN  0            // NB*NC*9 = 18432
#define OFF_GAMMA 18432        // 2048
#define OFF_BETA  20480        // 2048
#define OFF_ATT   22528        // 2048
#define OFF_A     24576        // 2048
#define OFF_B2    26624        // 2048
#define OFF_HMID  28672        // NB*128 = 1024
#define OFF_P     29696        // NB*NC*16 = 32768 (packed per-channel params, 64B/row)
#define OFF_GP    94208        // NB*16*130*130 = 2163200
#define OFF_APACK 2257408      // 8*16*64*8 bf16 = 65536 ushort = 32768 floats
#define OFF_PART  2322944      // 8*16*4*32 = 16384 floats

typedef __attribute__((ext_vector_type(8))) short bf16x8;
typedef __attribute__((ext_vector_type(4))) float f32x4;

__device__ __forceinline__ float leakyf(float v) { return v > 0.f ? v : 0.1f * v; }

__device__ __forceinline__ unsigned short f2bf(float f) {
    unsigned u = __float_as_uint(f);
    unsigned r = (u + 0x7FFFu + ((u >> 16) & 1u)) >> 16;
    return (unsigned short)r;
}
__device__ __forceinline__ float bf2f(unsigned short s) {
    return __uint_as_float(((unsigned)s) << 16);
}

// ---------------- K1: fused prep = params GEMVs + W pack + group sums ----------------
// blocks 0..367: per-sample GEMV rows; 368..623: w_conv2 pack; 624..1775: gsum
__global__ __launch_bounds__(256) void k_prep(
    const float* __restrict__ rep, const float* __restrict__ w_key,
    const float* __restrict__ w_gamma, const float* __restrict__ w_beta,
    const float* __restrict__ w_ca1, const float* __restrict__ prelu_a,
    const float* __restrict__ W, const float* __restrict__ x,
    float* __restrict__ ws)
{
    __shared__ float rep_s[NR];
    const int id = blockIdx.x;
    const int t = threadIdx.x;

    if (id < 368) {
        // ---- params: rows 0..2303 kern, 2304..2559 gamma, 2560..2815 beta, 2816..2943 hmid
        const int b = id / 46, rblk = id % 46;
        rep_s[t]       = rep[b*NR + t];
        rep_s[t + 256] = rep[b*NR + t + 256];
        __syncthreads();

        const int r = rblk * 64 + (t >> 2);   // 0..2943
        const int part = t & 3;
        const float* wrow;
        if (r < 2304)      wrow = w_key   + (size_t)r * NR;
        else if (r < 2560) wrow = w_gamma + (size_t)(r - 2304) * NR;
        else if (r < 2816) wrow = w_beta  + (size_t)(r - 2560) * NR;
        else               wrow = w_ca1   + (size_t)(r - 2816) * NR;

        const float4* w4 = (const float4*)wrow + part*32;
        const float4* r4 = (const float4*)rep_s + part*32;
        float acc = 0.f;
        #pragma unroll
        for (int i = 0; i < 32; i++) {
            float4 a = r4[i], w = w4[i];
            acc += a.x*w.x + a.y*w.y + a.z*w.z + a.w*w.w;
        }
        acc += __shfl_xor(acc, 1, 64);
        acc += __shfl_xor(acc, 2, 64);

        if (part == 0) {
            if (r < 2816) {
                const float v = leakyf(acc);
                if (r < 2304)      ws[OFF_KERN  + b*NC*9 + r]        = v;
                else if (r < 2560) ws[OFF_GAMMA + b*NC + r - 2304]   = v;
                else               ws[OFF_BETA  + b*NC + r - 2560]   = v;
            } else {
                const float pa = prelu_a[0];
                ws[OFF_HMID + b*128 + r - 2816] = acc > 0.f ? acc : pa * acc;
            }
        }
    } else if (id < 624) {
        // ---- pack w_conv2 into MFMA A-fragment order (bf16)
        const int idx = (id - 368) * 256 + t;   // 0..65535
        const int j    = idx & 7;
        const int lane = (idx >> 3) & 63;
        const int mt   = (idx >> 9) & 15;
        const int ks   = idx >> 13;
        const int m = mt*16 + (lane & 15);
        const int k = ks*32 + (lane >> 4)*8 + j;
        unsigned short* ap = (unsigned short*)(ws + OFF_APACK);
        ap[((ks*16 + mt)*64 + lane)*8 + j] = f2bf(W[m*NC + k]);
    } else {
        // ---- padded group sums (reflect): 8 px/thread, 2 independent f4 accumulators
        const int bid = id - 624;              // bg*9 + rg
        const int oc = t & 15;                 // px-octet (8 px each)
        const int r  = t >> 4;                 // row within group of 16
        const int rg = bid % 9;
        const int bg = bid / 9;                // b*16 + g
        const int yy = rg*16 + r;              // 0..143
        if (yy >= HP) return;
        int sy = yy - 1; if (sy < 0) sy = -sy; if (sy > NH-1) sy = 2*(NH-1) - sy;
        const float* xbase = x + (size_t)bg * 16 * NPIX + (size_t)sy * NW + oc*8;
        float4 s0 = make_float4(0.f, 0.f, 0.f, 0.f);
        float4 s1 = make_float4(0.f, 0.f, 0.f, 0.f);
        #pragma unroll
        for (int k = 0; k < 16; k++) {
            const float4 v0 = *(const float4*)(xbase + (size_t)k * NPIX);
            const float4 v1 = *(const float4*)(xbase + (size_t)k * NPIX + 4);
            s0.x += v0.x; s0.y += v0.y; s0.z += v0.z; s0.w += v0.w;
            s1.x += v1.x; s1.y += v1.y; s1.z += v1.z; s1.w += v1.w;
        }
        float* gp = ws + OFF_GP + ((size_t)bg * HP + yy) * HP + oc*8;
        gp[1] = s0.x; gp[2] = s0.y; gp[3] = s0.z; gp[4] = s0.w;
        gp[5] = s1.x; gp[6] = s1.y; gp[7] = s1.z; gp[8] = s1.w;
        if (oc == 0)  gp[0]         = s0.y;    // reflect: xsum[1]
        if (oc == 15) gp[129 - 120] = s1.z;    // gp[129] = xsum[126]
    }
}

// ---------------- K2: instance-norm partial stats from Gp, 4 px/thread ----------------
__global__ __launch_bounds__(256) void k_stats(float* __restrict__ ws)
{
    const int g = blockIdx.x, b = blockIdx.y, chunk = blockIdx.z, t = threadIdx.x;
    __shared__ float kern_s[16*9];
    __shared__ float red[256*32];
    if (t < 144) kern_s[t] = ws[OFF_KERN + (b*NC + g*16)*9 + t];
    __syncthreads();

    float s[16], q[16];
    #pragma unroll
    for (int i = 0; i < 16; i++) { s[i] = 0.f; q[i] = 0.f; }

    const float* gp = ws + OFF_GP + (size_t)(b*16 + g) * HP * HP;
    const int p0b = chunk * 4096;
    #pragma unroll
    for (int pi = 0; pi < 4; pi++) {
        const int p4 = p0b + pi*1024 + t*4;    // 4 consecutive px, same row (128%4==0)
        const int y = p4 >> 7, xc = p4 & 127;
        const float* pa = gp + y*HP + xc;
        float r0[6], r1[6], r2[6];
        #pragma unroll
        for (int c2 = 0; c2 < 3; c2++) {
            const float2 a0 = *(const float2*)(pa + c2*2);
            const float2 a1 = *(const float2*)(pa + HP + c2*2);
            const float2 a2 = *(const float2*)(pa + 2*HP + c2*2);
            r0[c2*2] = a0.x; r0[c2*2+1] = a0.y;
            r1[c2*2] = a1.x; r1[c2*2+1] = a1.y;
            r2[c2*2] = a2.x; r2[c2*2+1] = a2.y;
        }
        #pragma unroll
        for (int ch = 0; ch < 16; ch++) {
            const float* k9 = kern_s + ch*9;
            #pragma unroll
            for (int i = 0; i < 4; i++) {
                const float v = k9[0]*r0[i] + k9[1]*r0[i+1] + k9[2]*r0[i+2]
                              + k9[3]*r1[i] + k9[4]*r1[i+1] + k9[5]*r1[i+2]
                              + k9[6]*r2[i] + k9[7]*r2[i+1] + k9[8]*r2[i+2];
                s[ch] += v; q[ch] += v*v;
            }
        }
    }
    #pragma unroll
    for (int ch = 0; ch < 16; ch++) { red[t*32 + ch] = s[ch]; red[t*32 + 16 + ch] = q[ch]; }
    for (int st = 128; st >= 1; st >>= 1) {
        __syncthreads();
        if (t < st) {
            #pragma unroll
            for (int v = 0; v < 32; v++) red[t*32 + v] += red[(t+st)*32 + v];
        }
    }
    __syncthreads();
    if (t < 32) {
        ws[OFF_PART + (size_t)((b*16 + g)*4 + chunk)*32 + t] = red[t];
    }
}

// ---------------- K3: finalize stats -> packed params P[b][c][16] ----------------
__global__ __launch_bounds__(256) void k_fin(
    const float* __restrict__ w_ca2, float* __restrict__ ws)
{
    __shared__ float hm_s[128];
    const int b = blockIdx.x, c = threadIdx.x;
    if (c < 128) hm_s[c] = ws[OFF_HMID + b*128 + c];
    float* P = ws + OFF_P + ((size_t)(b*NC + c) << 4);
    {
        const int g = c >> 4, ch = c & 15;
        const float* part = ws + OFF_PART + (size_t)(b*16 + g)*4*32;
        float S = 0.f, Q = 0.f;
        #pragma unroll
        for (int k = 0; k < 4; k++) { S += part[k*32 + ch]; Q += part[k*32 + 16 + ch]; }
        const float mean = S * (1.f/16384.f);
        const float var  = Q * (1.f/16384.f) - mean*mean;
        const float inv  = rsqrtf(var + 1e-5f);
        const float ga = ws[OFF_GAMMA + b*NC + c];
        const float be = ws[OFF_BETA  + b*NC + c];
        const float a  = ga * inv;
        #pragma unroll
        for (int k = 0; k < 9; k++) P[k] = ws[OFF_KERN + (b*NC + c)*9 + k];
        P[9]  = a;
        P[10] = be - mean * a;
    }
    __syncthreads();
    {
        const float4* w4 = (const float4*)(w_ca2 + c*128);
        const float4* h4 = (const float4*)hm_s;
        float acc = 0.f;
        #pragma unroll
        for (int i = 0; i < 32; i++) {
            float4 a = h4[i], w = w4[i];
            acc += a.x*w.x + a.y*w.y + a.z*w.z + a.w*w.w;
        }
        P[11] = 1.f / (1.f + expf(-acc));
    }
}

// ---------------- K4: main fused kernel, 32-px blocks ----------------
// Phase B lane map: (pxq=lane&7 -> 4 px, chs=(lane>>3)&7 -> 8 ch), cvt_pk z-pack.
__global__ __launch_bounds__(256) void k_main(
    const float* __restrict__ x, const float* __restrict__ ws,
    const float* __restrict__ bias, float* __restrict__ out)
{
    // z_t: 32 px rows x 256 ch bf16; byte = px*512 + ((c*2) ^ ((px&31)<<4))
    __shared__ unsigned short z_t[32*256];     // 16384 B
    __shared__ float4 P_s[800];                // 12800 B (padded: +1 f4 per 8 ch)
    __shared__ float bias_s[NC];               // 1024 B  -> total 30208 B

    const int t = threadIdx.x;
    const int wave = t >> 6, lane = t & 63;
    const int x0 = blockIdx.x * 32, y = blockIdx.y, b = blockIdx.z;

    bias_s[t] = bias[t];

    // stage P into LDS with pad: dst = c*3 + k + (c>>3)
    {
        const float4* Pg = (const float4*)(ws + OFF_P + ((size_t)(b*NC) << 4));
        #pragma unroll
        for (int i = 0; i < 3; i++) {
            const int idx = t + i*256;          // 0..767 = c*3 + k
            const int c = idx / 3, k = idx - c*3;
            P_s[c*3 + k + (c >> 3)] = Pg[c*4 + k];
        }
    }

    char* zb = (char*)z_t;

    const int pxq = lane & 7;                   // 4-px quad
    const int chs = (lane >> 3) & 7;            // 8-ch sub
    const int cw8 = wave*64 + chs*8;            // lane's channel base (8 ch)
    const int g   = cw8 >> 4;                   // single group per lane
    const int px0g = x0 + pxq*4;                // first global px of the quad
    const float* gpB = ws + OFF_GP + (size_t)b * 16 * HP * HP;
    const unsigned short* ap = (const unsigned short*)(ws + OFF_APACK);
    const float* xB = x + (size_t)(b*NC + cw8) * NPIX + (size_t)y * NW + px0g;

    // ---- phase B loads: gp patch (3 rows x 6 floats, float2) + x (8 x float4) ----
    float gp6[3][6];
    {
        const float* gpr = gpB + ((size_t)g * HP + y) * HP + px0g;
        #pragma unroll
        for (int r = 0; r < 3; r++) {
            const float2 a0 = *(const float2*)(gpr + r*HP);
            const float2 a1 = *(const float2*)(gpr + r*HP + 2);
            const float2 a2 = *(const float2*)(gpr + r*HP + 4);
            gp6[r][0] = a0.x; gp6[r][1] = a0.y;
            gp6[r][2] = a1.x; gp6[r][3] = a1.y;
            gp6[r][4] = a2.x; gp6[r][5] = a2.y;
        }
    }
    float4 xq[8];
    #pragma unroll
    for (int j = 0; j < 8; j++) xq[j] = *(const float4*)(xB + (size_t)j * NPIX);

    __syncthreads();   // P_s ready

    // ---- phase B compute: 8 ch x 4 px per lane, channel-pair cvt_pk pack ----
    unsigned int wm[4][4];                       // [px][word]; word jp = ch 2jp,2jp+1
    const int base_f4 = cw8*3 + (cw8 >> 3);
    #pragma unroll
    for (int jp = 0; jp < 4; jp++) {
        const float4 qa0 = P_s[base_f4 + (2*jp)*3 + 0];
        const float4 qa1 = P_s[base_f4 + (2*jp)*3 + 1];
        const float4 qa2 = P_s[base_f4 + (2*jp)*3 + 2];
        const float4 qb0 = P_s[base_f4 + (2*jp+1)*3 + 0];
        const float4 qb1 = P_s[base_f4 + (2*jp+1)*3 + 1];
        const float4 qb2 = P_s[base_f4 + (2*jp+1)*3 + 2];
        const float xja[4] = {xq[2*jp].x,   xq[2*jp].y,   xq[2*jp].z,   xq[2*jp].w};
        const float xjb[4] = {xq[2*jp+1].x, xq[2*jp+1].y, xq[2*jp+1].z, xq[2*jp+1].w};
        #pragma unroll
        for (int i = 0; i < 4; i++) {
            const float cva =
                  gp6[0][i]*qa0.x + gp6[0][i+1]*qa0.y + gp6[0][i+2]*qa0.z
                + gp6[1][i]*qa0.w + gp6[1][i+1]*qa1.x + gp6[1][i+2]*qa1.y
                + gp6[2][i]*qa1.z + gp6[2][i+1]*qa1.w + gp6[2][i+2]*qa2.x;
            const float za = fmaxf(fmaf(qa2.y, cva, qa2.z), 0.f) + xja[i] * qa2.w;
            const float cvb =
                  gp6[0][i]*qb0.x + gp6[0][i+1]*qb0.y + gp6[0][i+2]*qb0.z
                + gp6[1][i]*qb0.w + gp6[1][i+1]*qb1.x + gp6[1][i+2]*qb1.y
                + gp6[2][i]*qb1.z + gp6[2][i+1]*qb1.w + gp6[2][i+2]*qb2.x;
            const float zbv = fmaxf(fmaf(qb2.y, cvb, qb2.z), 0.f) + xjb[i] * qb2.w;
            unsigned int w;
            asm("v_cvt_pk_bf16_f32 %0, %1, %2" : "=v"(w) : "v"(za), "v"(zbv));
            wm[i][jp] = w;
        }
    }
    // writes: 4 x b128; granule = (wave*8+chs) ^ (4*pxq+i) -> 2 lanes/granule (free)
    #pragma unroll
    for (int i = 0; i < 4; i++) {
        const int px = pxq*4 + i;
        *(uint4*)(zb + px*512 + ((cw8*2) ^ ((px & 31) << 4))) =
            make_uint4(wm[i][0], wm[i][1], wm[i][2], wm[i][3]);
    }
    __syncthreads();   // z ready

    // ---- phase C: out[o][px] via MFMA, K = 256, bias as C-init ----
    f32x4 acc[4][2];
    #pragma unroll
    for (int mi = 0; mi < 4; mi++) {
        const int o_base = wave*64 + mi*16 + (lane >> 4)*4;
        const f32x4 binit = *(const f32x4*)(&bias_s[o_base]);
        acc[mi][0] = binit;
        acc[mi][1] = binit;
    }

    #pragma unroll
    for (int ks = 0; ks < 8; ks++) {
        bf16x8 bfr[2];
        #pragma unroll
        for (int ni = 0; ni < 2; ni++) {
            const int pxc = ni*16 + (lane & 15);
            bfr[ni] = *(const bf16x8*)(zb + pxc*512 + ((ks*64 + (lane >> 4)*16) ^ ((pxc & 31) << 4)));
        }
        #pragma unroll
        for (int mi = 0; mi < 4; mi++) {
            const bf16x8 afr = *(const bf16x8*)(ap + ((size_t)((ks*16 + wave*4 + mi))*64 + lane)*8);
            #pragma unroll
            for (int ni = 0; ni < 2; ni++)
                acc[mi][ni] = __builtin_amdgcn_mfma_f32_16x16x32_bf16(afr, bfr[ni], acc[mi][ni], 0, 0, 0);
        }
    }

    // ---- epilogue: C layout col=lane&15 (px), row=(lane>>4)*4+reg (out) ----
    #pragma unroll
    for (int mi = 0; mi < 4; mi++) {
        const int o_base = wave*64 + mi*16 + (lane >> 4)*4;
        #pragma unroll
        for (int ni = 0; ni < 2; ni++) {
            const int px = x0 + ni*16 + (lane & 15);
            #pragma unroll
            for (int r = 0; r < 4; r++) {
                const int o = o_base + r;
                out[((size_t)(b*NC + o) * NH + y) * NW + px] = acc[mi][ni][r];
            }
        }
    }
}

extern "C" void kernel_launch(void* const* d_in, const int* in_sizes, int n_in,
                              void* d_out, int out_size, void* d_ws, size_t ws_size,
                              hipStream_t stream) {
    const float* x       = (const float*)d_in[0];
    const float* rep     = (const float*)d_in[1];
    const float* w_key   = (const float*)d_in[2];
    const float* w_gamma = (const float*)d_in[3];
    const float* w_beta  = (const float*)d_in[4];
    const float* w_ca1   = (const float*)d_in[5];
    const float* prelu_a = (const float*)d_in[6];
    const float* w_ca2   = (const float*)d_in[7];
    const float* w_conv2 = (const float*)d_in[8];
    const float* b_conv2 = (const float*)d_in[9];
    float* out = (float*)d_out;
    float* ws  = (float*)d_ws;

    k_prep<<<1776, 256, 0, stream>>>(rep, w_key, w_gamma, w_beta, w_ca1, prelu_a, w_conv2, x, ws);
    k_stats<<<dim3(NGROUPS, NB, 4), 256, 0, stream>>>(ws);
    k_fin<<<NB, 256, 0, stream>>>(w_ca2, ws);
    k_main<<<dim3(4, NH, NB), 256, 0, stream>>>(x, ws, b_conv2, out);
}

// Round 16
// 113.754 us; speedup vs baseline: 1.0775x; 1.0775x over previous
//
#include <hip/hip_runtime.h>
#include <hip/hip_bf16.h>

#define NB 8
#define NC 256
#define NH 128
#define NW 128
#define NR 512
#define NGROUPS 16
#define HP 130
#define NPIX (NH*NW)

// workspace offsets (in floats)
#define OFF_KERN  0            // NB*NC*9 = 18432
#define OFF_GAMMA 18432        // 2048
#define OFF_BETA  20480        // 2048
#define OFF_ATT   22528        // 2048
#define OFF_A     24576        // 2048
#define OFF_B2    26624        // 2048
#define OFF_HMID  28672        // NB*128 = 1024
#define OFF_P     29696        // NB*NC*16 = 32768 (packed per-channel params, 64B/row)
#define OFF_GP    94208        // NB*16*130*130 = 2163200
#define OFF_APACK 2257408      // 8*16*64*8 bf16 = 65536 ushort = 32768 floats
#define OFF_PART  2322944      // 8*16*4*32 = 16384 floats

typedef __attribute__((ext_vector_type(8))) short bf16x8;
typedef __attribute__((ext_vector_type(4))) float f32x4;

__device__ __forceinline__ float leakyf(float v) { return v > 0.f ? v : 0.1f * v; }

__device__ __forceinline__ unsigned short f2bf(float f) {
    unsigned u = __float_as_uint(f);
    unsigned r = (u + 0x7FFFu + ((u >> 16) & 1u)) >> 16;
    return (unsigned short)r;
}
__device__ __forceinline__ float bf2f(unsigned short s) {
    return __uint_as_float(((unsigned)s) << 16);
}

// ---------------- K1: fused prep = params GEMVs + W pack + group sums ----------------
// blocks 0..367: per-sample GEMV rows; 368..623: w_conv2 pack; 624..2799: gsum
__global__ __launch_bounds__(256) void k_prep(
    const float* __restrict__ rep, const float* __restrict__ w_key,
    const float* __restrict__ w_gamma, const float* __restrict__ w_beta,
    const float* __restrict__ w_ca1, const float* __restrict__ prelu_a,
    const float* __restrict__ W, const float* __restrict__ x,
    float* __restrict__ ws)
{
    __shared__ float rep_s[NR];
    const int id = blockIdx.x;
    const int t = threadIdx.x;

    if (id < 368) {
        // ---- params: rows 0..2303 kern, 2304..2559 gamma, 2560..2815 beta, 2816..2943 hmid
        const int b = id / 46, rblk = id % 46;
        rep_s[t]       = rep[b*NR + t];
        rep_s[t + 256] = rep[b*NR + t + 256];
        __syncthreads();

        const int r = rblk * 64 + (t >> 2);   // 0..2943
        const int part = t & 3;
        const float* wrow;
        if (r < 2304)      wrow = w_key   + (size_t)r * NR;
        else if (r < 2560) wrow = w_gamma + (size_t)(r - 2304) * NR;
        else if (r < 2816) wrow = w_beta  + (size_t)(r - 2560) * NR;
        else               wrow = w_ca1   + (size_t)(r - 2816) * NR;

        const float4* w4 = (const float4*)wrow + part*32;
        const float4* r4 = (const float4*)rep_s + part*32;
        float acc = 0.f;
        #pragma unroll
        for (int i = 0; i < 32; i++) {
            float4 a = r4[i], w = w4[i];
            acc += a.x*w.x + a.y*w.y + a.z*w.z + a.w*w.w;
        }
        acc += __shfl_xor(acc, 1, 64);
        acc += __shfl_xor(acc, 2, 64);

        if (part == 0) {
            if (r < 2816) {
                const float v = leakyf(acc);
                if (r < 2304)      ws[OFF_KERN  + b*NC*9 + r]        = v;
                else if (r < 2560) ws[OFF_GAMMA + b*NC + r - 2304]   = v;
                else               ws[OFF_BETA  + b*NC + r - 2560]   = v;
            } else {
                const float pa = prelu_a[0];
                ws[OFF_HMID + b*128 + r - 2816] = acc > 0.f ? acc : pa * acc;
            }
        }
    } else if (id < 624) {
        // ---- pack w_conv2 into MFMA A-fragment order (bf16)
        const int idx = (id - 368) * 256 + t;   // 0..65535
        const int j    = idx & 7;
        const int lane = (idx >> 3) & 63;
        const int mt   = (idx >> 9) & 15;
        const int ks   = idx >> 13;
        const int m = mt*16 + (lane & 15);
        const int k = ks*32 + (lane >> 4)*8 + j;
        unsigned short* ap = (unsigned short*)(ws + OFF_APACK);
        ap[((ks*16 + mt)*64 + lane)*8 + j] = f2bf(W[m*NC + k]);
    } else {
        // ---- padded group sums (reflect), vectorized
        const int bid = id - 624;              // bg*17 + rg
        const int l = t & 31;                  // px-quad index (4 px each)
        const int r = t >> 5;                  // row within group of 8
        const int rg = bid % 17;
        const int bg = bid / 17;               // b*16 + g
        const int yy = rg*8 + r;               // 0..135
        if (yy >= HP) return;
        int sy = yy - 1; if (sy < 0) sy = -sy; if (sy > NH-1) sy = 2*(NH-1) - sy;
        const float* xbase = x + (size_t)bg * 16 * NPIX + (size_t)sy * NW + l*4;
        float4 s = make_float4(0.f, 0.f, 0.f, 0.f);
        #pragma unroll
        for (int k = 0; k < 16; k++) {
            const float4 v = *(const float4*)(xbase + (size_t)k * NPIX);
            s.x += v.x; s.y += v.y; s.z += v.z; s.w += v.w;
        }
        float* gp = ws + OFF_GP + ((size_t)bg * HP + yy) * HP;
        gp[1 + l*4] = s.x;
        gp[2 + l*4] = s.y;
        gp[3 + l*4] = s.z;
        gp[4 + l*4] = s.w;
        if (l == 0)  gp[0]   = s.y;    // reflect: xsum[1]
        if (l == 31) gp[129] = s.z;    // reflect: xsum[126]
    }
}

// ---------------- K2: instance-norm partial stats from Gp ----------------
__global__ __launch_bounds__(256) void k_stats(float* __restrict__ ws)
{
    const int g = blockIdx.x, b = blockIdx.y, chunk = blockIdx.z, t = threadIdx.x;
    __shared__ float kern_s[16*9];
    __shared__ float red[256*32];
    if (t < 144) kern_s[t] = ws[OFF_KERN + (b*NC + g*16)*9 + t];
    __syncthreads();

    float s[16], q[16];
    #pragma unroll
    for (int i = 0; i < 16; i++) { s[i] = 0.f; q[i] = 0.f; }

    const float* gp = ws + OFF_GP + (size_t)(b*16 + g) * HP * HP;
    const int p0b = chunk * 4096;
    for (int pi = 0; pi < 16; pi++) {
        const int p = p0b + pi*256 + t;
        const int y = p >> 7, xc = p & 127;
        const float* pa = gp + y*HP + xc;
        const float p0 = pa[0],    p1 = pa[1],      p2 = pa[2];
        const float p3 = pa[HP],   p4 = pa[HP+1],   p5 = pa[HP+2];
        const float p6 = pa[2*HP], p7 = pa[2*HP+1], p8 = pa[2*HP+2];
        #pragma unroll
        for (int ch = 0; ch < 16; ch++) {
            const float* k9 = kern_s + ch*9;
            float v = k9[0]*p0 + k9[1]*p1 + k9[2]*p2
                    + k9[3]*p3 + k9[4]*p4 + k9[5]*p5
                    + k9[6]*p6 + k9[7]*p7 + k9[8]*p8;
            s[ch] += v; q[ch] += v*v;
        }
    }
    #pragma unroll
    for (int ch = 0; ch < 16; ch++) { red[t*32 + ch] = s[ch]; red[t*32 + 16 + ch] = q[ch]; }
    for (int st = 128; st >= 1; st >>= 1) {
        __syncthreads();
        if (t < st) {
            #pragma unroll
            for (int v = 0; v < 32; v++) red[t*32 + v] += red[(t+st)*32 + v];
        }
    }
    __syncthreads();
    if (t < 32) {
        ws[OFF_PART + (size_t)((b*16 + g)*4 + chunk)*32 + t] = red[t];
    }
}

// ---------------- K3: finalize stats -> packed params P[b][c][16] ----------------
__global__ __launch_bounds__(256) void k_fin(
    const float* __restrict__ w_ca2, float* __restrict__ ws)
{
    __shared__ float hm_s[128];
    const int b = blockIdx.x, c = threadIdx.x;
    if (c < 128) hm_s[c] = ws[OFF_HMID + b*128 + c];
    float* P = ws + OFF_P + ((size_t)(b*NC + c) << 4);
    {
        const int g = c >> 4, ch = c & 15;
        const float* part = ws + OFF_PART + (size_t)(b*16 + g)*4*32;
        float S = 0.f, Q = 0.f;
        #pragma unroll
        for (int k = 0; k < 4; k++) { S += part[k*32 + ch]; Q += part[k*32 + 16 + ch]; }
        const float mean = S * (1.f/16384.f);
        const float var  = Q * (1.f/16384.f) - mean*mean;
        const float inv  = rsqrtf(var + 1e-5f);
        const float ga = ws[OFF_GAMMA + b*NC + c];
        const float be = ws[OFF_BETA  + b*NC + c];
        const float a  = ga * inv;
        #pragma unroll
        for (int k = 0; k < 9; k++) P[k] = ws[OFF_KERN + (b*NC + c)*9 + k];
        P[9]  = a;
        P[10] = be - mean * a;
    }
    __syncthreads();
    {
        const float4* w4 = (const float4*)(w_ca2 + c*128);
        const float4* h4 = (const float4*)hm_s;
        float acc = 0.f;
        #pragma unroll
        for (int i = 0; i < 32; i++) {
            float4 a = h4[i], w = w4[i];
            acc += a.x*w.x + a.y*w.y + a.z*w.z + a.w*w.w;
        }
        P[11] = 1.f / (1.f + expf(-acc));
    }
}

// ---------------- K4: main fused kernel, 32-px blocks ----------------
// Phase B lane map: (pxq=lane&7 -> 4 px, chs=(lane>>3)&7 -> 8 ch), cvt_pk z-pack.
__global__ __launch_bounds__(256) void k_main(
    const float* __restrict__ x, const float* __restrict__ ws,
    const float* __restrict__ bias, float* __restrict__ out)
{
    // z_t: 32 px rows x 256 ch bf16; byte = px*512 + ((c*2) ^ ((px&31)<<4))
    __shared__ unsigned short z_t[32*256];     // 16384 B
    __shared__ float4 P_s[800];                // 12800 B (padded: +1 f4 per 8 ch)
    __shared__ float bias_s[NC];               // 1024 B  -> total 30208 B

    const int t = threadIdx.x;
    const int wave = t >> 6, lane = t & 63;
    const int x0 = blockIdx.x * 32, y = blockIdx.y, b = blockIdx.z;

    bias_s[t] = bias[t];

    // stage P into LDS with pad: dst = c*3 + k + (c>>3)
    {
        const float4* Pg = (const float4*)(ws + OFF_P + ((size_t)(b*NC) << 4));
        #pragma unroll
        for (int i = 0; i < 3; i++) {
            const int idx = t + i*256;          // 0..767 = c*3 + k
            const int c = idx / 3, k = idx - c*3;
            P_s[c*3 + k + (c >> 3)] = Pg[c*4 + k];
        }
    }

    char* zb = (char*)z_t;

    const int pxq = lane & 7;                   // 4-px quad
    const int chs = (lane >> 3) & 7;            // 8-ch sub
    const int cw8 = wave*64 + chs*8;            // lane's channel base (8 ch)
    const int g   = cw8 >> 4;                   // single group per lane
    const int px0g = x0 + pxq*4;                // first global px of the quad
    const float* gpB = ws + OFF_GP + (size_t)b * 16 * HP * HP;
    const unsigned short* ap = (const unsigned short*)(ws + OFF_APACK);
    const float* xB = x + (size_t)(b*NC + cw8) * NPIX + (size_t)y * NW + px0g;

    // ---- phase B loads: gp patch (3 rows x 6 floats, float2) + x (8 x float4) ----
    float gp6[3][6];
    {
        const float* gpr = gpB + ((size_t)g * HP + y) * HP + px0g;
        #pragma unroll
        for (int r = 0; r < 3; r++) {
            const float2 a0 = *(const float2*)(gpr + r*HP);
            const float2 a1 = *(const float2*)(gpr + r*HP + 2);
            const float2 a2 = *(const float2*)(gpr + r*HP + 4);
            gp6[r][0] = a0.x; gp6[r][1] = a0.y;
            gp6[r][2] = a1.x; gp6[r][3] = a1.y;
            gp6[r][4] = a2.x; gp6[r][5] = a2.y;
        }
    }
    float4 xq[8];
    #pragma unroll
    for (int j = 0; j < 8; j++) xq[j] = *(const float4*)(xB + (size_t)j * NPIX);

    __syncthreads();   // P_s ready

    // ---- phase B compute: 8 ch x 4 px per lane, channel-pair cvt_pk pack ----
    unsigned int wm[4][4];                       // [px][word]; word jp = ch 2jp,2jp+1
    const int base_f4 = cw8*3 + (cw8 >> 3);
    #pragma unroll
    for (int jp = 0; jp < 4; jp++) {
        const float4 qa0 = P_s[base_f4 + (2*jp)*3 + 0];
        const float4 qa1 = P_s[base_f4 + (2*jp)*3 + 1];
        const float4 qa2 = P_s[base_f4 + (2*jp)*3 + 2];
        const float4 qb0 = P_s[base_f4 + (2*jp+1)*3 + 0];
        const float4 qb1 = P_s[base_f4 + (2*jp+1)*3 + 1];
        const float4 qb2 = P_s[base_f4 + (2*jp+1)*3 + 2];
        const float xja[4] = {xq[2*jp].x,   xq[2*jp].y,   xq[2*jp].z,   xq[2*jp].w};
        const float xjb[4] = {xq[2*jp+1].x, xq[2*jp+1].y, xq[2*jp+1].z, xq[2*jp+1].w};
        #pragma unroll
        for (int i = 0; i < 4; i++) {
            const float cva =
                  gp6[0][i]*qa0.x + gp6[0][i+1]*qa0.y + gp6[0][i+2]*qa0.z
                + gp6[1][i]*qa0.w + gp6[1][i+1]*qa1.x + gp6[1][i+2]*qa1.y
                + gp6[2][i]*qa1.z + gp6[2][i+1]*qa1.w + gp6[2][i+2]*qa2.x;
            const float za = fmaxf(fmaf(qa2.y, cva, qa2.z), 0.f) + xja[i] * qa2.w;
            const float cvb =
                  gp6[0][i]*qb0.x + gp6[0][i+1]*qb0.y + gp6[0][i+2]*qb0.z
                + gp6[1][i]*qb0.w + gp6[1][i+1]*qb1.x + gp6[1][i+2]*qb1.y
                + gp6[2][i]*qb1.z + gp6[2][i+1]*qb1.w + gp6[2][i+2]*qb2.x;
            const float zbv = fmaxf(fmaf(qb2.y, cvb, qb2.z), 0.f) + xjb[i] * qb2.w;
            unsigned int w;
            asm("v_cvt_pk_bf16_f32 %0, %1, %2" : "=v"(w) : "v"(za), "v"(zbv));
            wm[i][jp] = w;
        }
    }
    // writes: 4 x b128; granule = (wave*8+chs) ^ (4*pxq+i) -> 2 lanes/granule (free)
    #pragma unroll
    for (int i = 0; i < 4; i++) {
        const int px = pxq*4 + i;
        *(uint4*)(zb + px*512 + ((cw8*2) ^ ((px & 31) << 4))) =
            make_uint4(wm[i][0], wm[i][1], wm[i][2], wm[i][3]);
    }
    __syncthreads();   // z ready

    // ---- phase C: out[o][px] via MFMA, K = 256, bias as C-init ----
    f32x4 acc[4][2];
    #pragma unroll
    for (int mi = 0; mi < 4; mi++) {
        const int o_base = wave*64 + mi*16 + (lane >> 4)*4;
        const f32x4 binit = *(const f32x4*)(&bias_s[o_base]);
        acc[mi][0] = binit;
        acc[mi][1] = binit;
    }

    #pragma unroll
    for (int ks = 0; ks < 8; ks++) {
        bf16x8 bfr[2];
        #pragma unroll
        for (int ni = 0; ni < 2; ni++) {
            const int pxc = ni*16 + (lane & 15);
            bfr[ni] = *(const bf16x8*)(zb + pxc*512 + ((ks*64 + (lane >> 4)*16) ^ ((pxc & 31) << 4)));
        }
        #pragma unroll
        for (int mi = 0; mi < 4; mi++) {
            const bf16x8 afr = *(const bf16x8*)(ap + ((size_t)((ks*16 + wave*4 + mi))*64 + lane)*8);
            #pragma unroll
            for (int ni = 0; ni < 2; ni++)
                acc[mi][ni] = __builtin_amdgcn_mfma_f32_16x16x32_bf16(afr, bfr[ni], acc[mi][ni], 0, 0, 0);
        }
    }

    // ---- epilogue: C layout col=lane&15 (px), row=(lane>>4)*4+reg (out) ----
    #pragma unroll
    for (int mi = 0; mi < 4; mi++) {
        const int o_base = wave*64 + mi*16 + (lane >> 4)*4;
        #pragma unroll
        for (int ni = 0; ni < 2; ni++) {
            const int px = x0 + ni*16 + (lane & 15);
            #pragma unroll
            for (int r = 0; r < 4; r++) {
                const int o = o_base + r;
                out[((size_t)(b*NC + o) * NH + y) * NW + px] = acc[mi][ni][r];
            }
        }
    }
}

extern "C" void kernel_launch(void* const* d_in, const int* in_sizes, int n_in,
                              void* d_out, int out_size, void* d_ws, size_t ws_size,
                              hipStream_t stream) {
    const float* x       = (const float*)d_in[0];
    const float* rep     = (const float*)d_in[1];
    const float* w_key   = (const float*)d_in[2];
    const float* w_gamma = (const float*)d_in[3];
    const float* w_beta  = (const float*)d_in[4];
    const float* w_ca1   = (const float*)d_in[5];
    const float* prelu_a = (const float*)d_in[6];
    const float* w_ca2   = (const float*)d_in[7];
    const float* w_conv2 = (const float*)d_in[8];
    const float* b_conv2 = (const float*)d_in[9];
    float* out = (float*)d_out;
    float* ws  = (float*)d_ws;

    k_prep<<<2800, 256, 0, stream>>>(rep, w_key, w_gamma, w_beta, w_ca1, prelu_a, w_conv2, x, ws);
    k_stats<<<dim3(NGROUPS, NB, 4), 256, 0, stream>>>(ws);
    k_fin<<<NB, 256, 0, stream>>>(w_ca2, ws);
    k_main<<<dim3(4, NH, NB), 256, 0, stream>>>(x, ws, b_conv2, out);
}